// Round 8
// baseline (278.317 us; speedup 1.0000x reference)
//
#include <hip/hip_runtime.h>

// BalancedCELoss: loss = -mean( t==1 ? 2*log(p) : 1*log1p(-p) ), N = 33554432.
// 256 MB traffic, ~41 us roofline at 6.3 TB/s.
// R1/R2/R5/R7: ~104-130 us (2.5 TB/s effective), INVARIANT to L3-vs-HBM
// residency and to forced per-wave ILP (compiler defeats it via AGPR parking).
// R8 single-axis experiment: contiguous-per-block mapping. Block b owns
// float4s [b*4096, (b+1)*4096) of each array (64 KB windows, sequential),
// instead of the 8 MB-strided device-wide interleave. Plain R1-style loop.

#define GRID  2048
#define BLOCK 256
#define ITERS 16
#define LN2F  0.69314718055994531f

// per element: x = t ? p : 1-p ; w = 1+t ; acc += w * log2(x)  (scale by -ln2/N later)
__device__ __forceinline__ void acc4(const float4 pv, const int4 tv, float& acc) {
  float tf0 = (float)tv.x, tf1 = (float)tv.y, tf2 = (float)tv.z, tf3 = (float)tv.w;
  float x0 = __builtin_fmaf(tf0, __builtin_fmaf(2.f, pv.x, -1.f), 1.f - pv.x);
  float x1 = __builtin_fmaf(tf1, __builtin_fmaf(2.f, pv.y, -1.f), 1.f - pv.y);
  float x2 = __builtin_fmaf(tf2, __builtin_fmaf(2.f, pv.z, -1.f), 1.f - pv.z);
  float x3 = __builtin_fmaf(tf3, __builtin_fmaf(2.f, pv.w, -1.f), 1.f - pv.w);
  float l0 = __log2f(x0), l1 = __log2f(x1), l2 = __log2f(x2), l3 = __log2f(x3);
  acc += l0; acc = __builtin_fmaf(tf0, l0, acc);
  acc += l1; acc = __builtin_fmaf(tf1, l1, acc);
  acc += l2; acc = __builtin_fmaf(tf2, l2, acc);
  acc += l3; acc = __builtin_fmaf(tf3, l3, acc);
}

__global__ __launch_bounds__(BLOCK) void bce_reduce_kernel(
    const float* __restrict__ p, const int* __restrict__ t,
    float* __restrict__ partial, int n4) {
  const float4* p4 = (const float4*)p;
  const int4*   t4 = (const int4*)t;

  float acc = 0.f;

  const int per_block = ITERS * BLOCK;  // 4096 float4s = 64 KB per array
  if (n4 == GRID * per_block) {
    // contiguous window per block; thread walks it at BLOCK-float4 stride
    const int base = blockIdx.x * per_block + threadIdx.x;
    #pragma unroll
    for (int i = 0; i < ITERS; ++i) {
      float4 pv = p4[base + i * BLOCK];
      int4   tv = t4[base + i * BLOCK];
      acc4(pv, tv, acc);
    }
  } else {
    // generic grid-stride fallback
    const int idx = blockIdx.x * BLOCK + threadIdx.x;
    const int S   = GRID * BLOCK;
    for (int i = idx; i < n4; i += S) {
      float4 pv = p4[i];
      int4   tv = t4[i];
      acc4(pv, tv, acc);
    }
  }

  // wave-64 reduce
  #pragma unroll
  for (int off = 32; off > 0; off >>= 1)
    acc += __shfl_down(acc, off, 64);

  __shared__ float s[BLOCK / 64];
  const int wave = threadIdx.x >> 6;
  if ((threadIdx.x & 63) == 0) s[wave] = acc;
  __syncthreads();

  if (threadIdx.x == 0)
    partial[blockIdx.x] = (s[0] + s[1]) + (s[2] + s[3]);
}

// Reduce GRID partials -> out = -sum * ln2 / N   (partials are in log2 units)
__global__ __launch_bounds__(256) void bce_finalize_kernel(
    const float* __restrict__ partial, float* __restrict__ out, float scale) {
  float acc = 0.f;
  for (int i = threadIdx.x; i < GRID; i += 256)
    acc += partial[i];
  #pragma unroll
  for (int off = 32; off > 0; off >>= 1)
    acc += __shfl_down(acc, off, 64);
  __shared__ float s[4];
  const int wave = threadIdx.x >> 6;
  if ((threadIdx.x & 63) == 0) s[wave] = acc;
  __syncthreads();
  if (threadIdx.x == 0)
    out[0] = ((s[0] + s[1]) + (s[2] + s[3])) * scale;
}

extern "C" void kernel_launch(void* const* d_in, const int* in_sizes, int n_in,
                              void* d_out, int out_size, void* d_ws, size_t ws_size,
                              hipStream_t stream) {
  const float* p = (const float*)d_in[0];
  const int*   t = (const int*)d_in[1];
  float* out = (float*)d_out;
  float* ws  = (float*)d_ws;  // GRID floats of per-block partials (all overwritten)

  const int n  = in_sizes[0];
  const int n4 = n / 4;

  bce_reduce_kernel<<<GRID, BLOCK, 0, stream>>>(p, t, ws, n4);
  bce_finalize_kernel<<<1, 256, 0, stream>>>(ws, out, -LN2F / (float)n);
}